// Round 20
// baseline (58.068 us; speedup 1.0000x reference)
//
#include <hip/hip_runtime.h>
#include <hip/hip_bf16.h>
#include <math.h>

// NoisyTopExpertsPerItemRouter: B=8,S=4096,D=1024,E=64,K=2
#define B_ 8
#define S_ 4096
#define D_ 1024
#define E_ 64
#define NOISE_STD 0.015625f     // max(1/64, 1e-6)
#define INV_NOISE_STD 64.0f
#define OUT_GATES (B_ * S_ * E_)   // 2097152
#define NBLK 1024                  // main grid = S_/4 (32 rows per block)
#define RBLK 32                    // reduce grid

typedef __attribute__((ext_vector_type(8))) short short8;
typedef __attribute__((ext_vector_type(4))) float f32x4;

// workspace layout (float offsets)
// [0 .. 32768): Wg as bf16 [64][1024] (ushort)
#define WS_GW   32768                    // GW[64]
#define WS_BW   32832                    // BW[64]
#define WS_PART 32896                    // part[1024][644] per-block records
#define PART_STRIDE 644                  // 512 imp + 64 sgn + 64 cnt + c1 + c2
#define WS_TOT  (WS_PART + NBLK * PART_STRIDE)
#define N_TOT   642
#define WS_FLAG (WS_TOT + N_TOT)         // completion counter (zeroed by prep)

// K-loop barrier WITHOUT the vmcnt(0) drain __syncthreads would emit.
#define LDS_BARRIER() \
  asm volatile("s_waitcnt lgkmcnt(0)\n\ts_barrier" ::: "memory")

__device__ __forceinline__ float wave_sum64(float v) {
#pragma unroll
  for (int o = 32; o > 0; o >>= 1) v += __shfl_xor(v, o);
  return v;
}

// ---------------- prep: Wg(bf16) = gamma*W, GW/BW reductions, zero totals ---
__global__ void router_prep(const float* __restrict__ W,
                            const float* __restrict__ gamma,
                            const float* __restrict__ beta,
                            float* __restrict__ ws) {
  if (blockIdx.x >= E_) {
    for (int i = threadIdx.x; i < N_TOT + 1; i += 256) ws[WS_TOT + i] = 0.0f;
    return;
  }
  const int e = blockIdx.x;
  unsigned short* wgb = (unsigned short*)ws;
  float gw = 0.0f, bw = 0.0f;
  for (int d = threadIdx.x; d < D_; d += 256) {
    float wv = W[e * D_ + d];
    float pv = gamma[d] * wv;
    union { __hip_bfloat16 h; unsigned short u; } cv;
    cv.h = __float2bfloat16(pv);
    wgb[e * D_ + d] = cv.u;
    gw += __bfloat162float(cv.h);   // sum of ROUNDED values (consistency)
    bw += beta[d] * wv;
  }
  __shared__ float sred[8];
  gw = wave_sum64(gw);
  bw = wave_sum64(bw);
  const int w = threadIdx.x >> 6, lane = threadIdx.x & 63;
  if (lane == 0) { sred[w] = gw; sred[4 + w] = bw; }
  __syncthreads();
  if (threadIdx.x == 0) {
    ws[WS_GW + e] = sred[0] + sred[1] + sred[2] + sred[3];
    ws[WS_BW + e] = sred[4] + sred[5] + sred[6] + sred[7];
  }
}

// ---------------- main: R16 + bf16 A-tile (cvt at staging, 1 b128/MFMA) -----
// block = 512 thr = 8 waves; owns 32 rows (r: b=r&7, sl=r>>3, s=4*bid+sl).
// Wave w: rg=w>>2 (16 rows), et=w&3 (16 experts), FULL K -> acc = 1 f32x4.
// A-tile stored as BF16 [32 rows][64 bf16] (= [32][32] dwords): f32->bf16
// conversion moved to staging (1x per element vs 4x redundant in-loop).
// Swizzle: logical 16B granule g = 4ks+kh stored at g^(row&7) -> reads 8
// lanes/4-bank group (min, conflict-free); writes 32 banks/row (min).
// A-fragment = ONE contiguous ds_read_b128 per MFMA (was 2). lgkm-only
// barriers; X queue depth 2; B ring depth 2; fused reduce+final tail (R19).
__global__ void __launch_bounds__(512, 4)
router_main(const float* __restrict__ X, const float* __restrict__ noise,
            float* __restrict__ out, float* __restrict__ ws) {
  __shared__ __align__(16) unsigned int xbuf[2][1024];  // 2 x [32][32] dwords (bf16 tile)
  __shared__ __align__(16) float gclgnl[4352];          // [32][68] x2 gates
  __shared__ __align__(16) float Lg[2176];              // [32][68] logits; -> pl
  __shared__ float svs[32], sv2s[32];
  __shared__ float cntl[64];
  __shared__ float red8[8];
  float* gcl = gclgnl;           // [32][68] clean gates
  float* gnl = gclgnl + 2176;    // [32][68] noisy gates
  float* pl  = Lg;               // per-lane read-then-write -> safe alias

  const int t = threadIdx.x;
  const int w = t >> 6, lane = t & 63;
  const int lrow = lane & 15, kh = lane >> 4;
  const int bid = blockIdx.x;
  const int s0 = bid * 4;

  // staging: thread t -> row r_t = t>>4, f32 cols c4w*4..+3 -> 2 dwords bf16,
  // written into physical granule (c4w>>1)^(r_t&7), half = c4w&1.
  const int r_t = t >> 4, c4w = t & 15;
  const int wdw = r_t * 32 + (((c4w >> 1) ^ (r_t & 7)) << 2) + (c4w & 1) * 2;
  const float* __restrict__ xstage =
      X + ((size_t)(r_t & 7) * S_ + (size_t)(s0 + (r_t >> 3))) * D_ + c4w * 4;

  // GEMM: wave w -> rg = w>>2 (rows 16rg..16rg+15), et = w&3 (experts 16et..)
  const int rg = w >> 2, et = w & 3;
  const unsigned short* __restrict__ bp =
      (const unsigned short*)ws + (16 * et + lrow) * D_ + kh * 8;
  const float gwv = ws[WS_GW + 16 * et + lrow];
  const float bwv = ws[WS_BW + 16 * et + lrow];

  // A-read swizzled dword offsets: logical granule ks*4+kh at ^(lrow&7)
  const int arow = (16 * rg + lrow) * 32;
  const int rdw0 = arow + (((0 + kh) ^ (lrow & 7)) << 2);   // ks=0
  const int rdw1 = arow + (((4 + kh) ^ (lrow & 7)) << 2);   // ks=1

  // epilogue indices + EARLY noise load (lands during GEMM)
  const int rr_e = lane >> 4, j_e = lane & 15;
  const int r_e = w * 4 + rr_e;                 // [0,32)
  const int b_e = r_e & 7, sl_e = r_e >> 3;
  const int s_e = s0 + sl_e;
  const float4 nv =
      *(const float4*)(noise + ((size_t)b_e * S_ + s_e) * E_ + 4 * j_e);

  // prologue: X regs for steps 0,1; B ring for steps 0,1; stage step 0
  float4 qx[2];
  short8 qb[2][2];
  qx[0] = *(const float4*)(xstage);
  qx[1] = *(const float4*)(xstage + 64);
  qb[0][0] = *(const short8*)(bp);
  qb[0][1] = *(const short8*)(bp + 32);
  qb[1][0] = *(const short8*)(bp + 64);
  qb[1][1] = *(const short8*)(bp + 96);

  float ssv = 0.0f, ssv2 = 0.0f;
  {
    union { __hip_bfloat162 h; unsigned int u; } c0, c1;
    c0.h = __float22bfloat162_rn(make_float2(qx[0].x, qx[0].y));
    c1.h = __float22bfloat162_rn(make_float2(qx[0].z, qx[0].w));
    *(uint2*)&xbuf[0][wdw] = make_uint2(c0.u, c1.u);
    ssv  += (qx[0].x + qx[0].y) + (qx[0].z + qx[0].w);
    ssv2 = fmaf(qx[0].x, qx[0].x, ssv2); ssv2 = fmaf(qx[0].y, qx[0].y, ssv2);
    ssv2 = fmaf(qx[0].z, qx[0].z, ssv2); ssv2 = fmaf(qx[0].w, qx[0].w, ssv2);
  }

  f32x4 acc = {0.f, 0.f, 0.f, 0.f};

#pragma unroll
  for (int s = 0; s < 16; ++s) {
    LDS_BARRIER();                         // buf[s&1] staged (no vmcnt drain)
    if (s + 2 < 16)                        // X for step s+2 (slot s&1 now free)
      qx[s & 1] = *(const float4*)(xstage + (s + 2) * 64);

    const unsigned int* xb = xbuf[s & 1];
    {
      short8 av = *(const short8*)&xb[rdw0];
      acc = __builtin_amdgcn_mfma_f32_16x16x32_bf16(av, qb[s & 1][0],
                                                    acc, 0, 0, 0);
    }
    {
      short8 av = *(const short8*)&xb[rdw1];
      acc = __builtin_amdgcn_mfma_f32_16x16x32_bf16(av, qb[s & 1][1],
                                                    acc, 0, 0, 0);
    }
    if (s + 2 < 16) {                      // refill B ring slot just consumed
      qb[s & 1][0] = *(const short8*)(bp + (s + 2) * 64);
      qb[s & 1][1] = *(const short8*)(bp + (s + 2) * 64 + 32);
    }
    if (s + 1 < 16) {                      // stage step s+1 (issued at s-1)
      float4 wv = qx[(s + 1) & 1];
      union { __hip_bfloat162 h; unsigned int u; } c0, c1;
      c0.h = __float22bfloat162_rn(make_float2(wv.x, wv.y));
      c1.h = __float22bfloat162_rn(make_float2(wv.z, wv.w));
      *(uint2*)&xbuf[(s + 1) & 1][wdw] = make_uint2(c0.u, c1.u);
      ssv  += (wv.x + wv.y) + (wv.z + wv.w);
      ssv2 = fmaf(wv.x, wv.x, ssv2); ssv2 = fmaf(wv.y, wv.y, ssv2);
      ssv2 = fmaf(wv.z, wv.z, ssv2); ssv2 = fmaf(wv.w, wv.w, ssv2);
    }
  }

  // LN stats: 16 staging threads per row -> shfl reduce within 16-lane group
  ssv  += __shfl_xor(ssv, 1);  ssv  += __shfl_xor(ssv, 2);
  ssv  += __shfl_xor(ssv, 4);  ssv  += __shfl_xor(ssv, 8);
  ssv2 += __shfl_xor(ssv2, 1); ssv2 += __shfl_xor(ssv2, 2);
  ssv2 += __shfl_xor(ssv2, 4); ssv2 += __shfl_xor(ssv2, 8);
  if ((t & 15) == 0) { svs[r_t] = ssv; sv2s[r_t] = ssv2; }
  if (t < 64) cntl[t] = 0.0f;
  __syncthreads();

  // logits: C/D layout col=lane&15, row=(lane>>4)*4+i  [m89-verified]
#pragma unroll
  for (int i = 0; i < 4; i++) {
    const int rloc = 16 * rg + kh * 4 + i;
    const float mui = svs[rloc] * (1.0f / (float)D_);
    const float var = sv2s[rloc] * (1.0f / (float)D_) - mui * mui;
    const float rsi = rsqrtf(var + 1e-5f);
    Lg[rloc * 68 + 16 * et + lrow] = rsi * (acc[i] - mui * gwv) + bwv;
  }
  __syncthreads();   // logits ready

  // ---- epilogue: 8 waves; wave w rows 4w..4w+3; lane=(rr,j), 4 experts ----
  {
    const int r = r_e, b = b_e, s = s_e, j = j_e;
    float4 lv = *(const float4*)(Lg + r * 68 + 4 * j);
    float ln0 = fmaf(NOISE_STD, nv.x, lv.x);
    float ln1 = fmaf(NOISE_STD, nv.y, lv.y);
    float ln2 = fmaf(NOISE_STD, nv.z, lv.z);
    float ln3 = fmaf(NOISE_STD, nv.w, lv.w);

    // combined max+secondmax of noisy logits (m1 also shifts clean softmax)
    float m1 = ln0, m2 = -INFINITY;
    m2 = fmaxf(m2, fminf(m1, ln1)); m1 = fmaxf(m1, ln1);
    m2 = fmaxf(m2, fminf(m1, ln2)); m1 = fmaxf(m1, ln2);
    m2 = fmaxf(m2, fminf(m1, ln3)); m1 = fmaxf(m1, ln3);
#pragma unroll
    for (int o = 1; o <= 8; o <<= 1) {
      float o1 = __shfl_xor(m1, o), o2 = __shfl_xor(m2, o);
      m2 = fmaxf(fmaxf(m2, o2), fminf(m1, o1));
      m1 = fmaxf(m1, o1);
    }
    float ec0 = __expf(lv.x - m1), ec1 = __expf(lv.y - m1);
    float ec2 = __expf(lv.z - m1), ec3 = __expf(lv.w - m1);
    float en0 = __expf(ln0 - m1), en1 = __expf(ln1 - m1);
    float en2 = __expf(ln2 - m1), en3 = __expf(ln3 - m1);
    float sg = (ec0 + ec1) + (ec2 + ec3);
    float sn = (en0 + en1) + (en2 + en3);
#pragma unroll
    for (int o = 1; o <= 8; o <<= 1) {
      sg += __shfl_xor(sg, o);
      sn += __shfl_xor(sn, o);
    }
    const float rg_ = 1.0f / sg, rn_ = 1.0f / sn;
    float4 gnv = { en0 * rn_, en1 * rn_, en2 * rn_, en3 * rn_ };
    float4 gcv = { ec0 * rg_, ec1 * rg_, ec2 * rg_, ec3 * rg_ };
    float z0 = fminf(fmaxf((m2 - lv.x) * INV_NOISE_STD, -10.f), 10.f);
    float z1 = fminf(fmaxf((m2 - lv.y) * INV_NOISE_STD, -10.f), 10.f);
    float z2 = fminf(fmaxf((m2 - lv.z) * INV_NOISE_STD, -10.f), 10.f);
    float z3 = fminf(fmaxf((m2 - lv.w) * INV_NOISE_STD, -10.f), 10.f);
    float4 pv = { 0.5f * (1.0f + erff(z0 * 0.70710678118654752f)),
                  0.5f * (1.0f + erff(z1 * 0.70710678118654752f)),
                  0.5f * (1.0f + erff(z2 * 0.70710678118654752f)),
                  0.5f * (1.0f + erff(z3 * 0.70710678118654752f)) };

    *(float4*)(out + ((size_t)b * S_ + s) * E_ + 4 * j) = gnv;
    *(float4*)(gnl + r * 68 + 4 * j) = gnv;
    *(float4*)(gcl + r * 68 + 4 * j) = gcv;
    *(float4*)(pl  + r * 68 + 4 * j) = pv;
    // top-1 count via equality (ties vanishingly rare; softmax is monotone)
    if (ln0 == m1) atomicAdd(&cntl[4 * j + 0], 1.0f);
    if (ln1 == m1) atomicAdd(&cntl[4 * j + 1], 1.0f);
    if (ln2 == m1) atomicAdd(&cntl[4 * j + 2], 1.0f);
    if (ln3 == m1) atomicAdd(&cntl[4 * j + 3], 1.0f);
  }
  __syncthreads();

  // ---- phase 2: block reductions -> PLAIN per-block record (no atomics) ----
  float* prt = ws + WS_PART + (size_t)bid * PART_STRIDE;
  {
    // importance: thread t -> (b = t>>6, e = t&63), sum over 4 sl
    const int b0i = t >> 6, e0i = t & 63;
    float v = gcl[(0 * 8 + b0i) * 68 + e0i] + gcl[(1 * 8 + b0i) * 68 + e0i] +
              gcl[(2 * 8 + b0i) * 68 + e0i] + gcl[(3 * 8 + b0i) * 68 + e0i];
    prt[t] = v;
  }
  if (t < 64) {
    float sgn = 0.0f;
#pragma unroll
    for (int r = 0; r < 32; r++) sgn += gnl[r * 68 + t];
    prt[512 + t] = sgn;
  } else if (t < 128) {
    prt[576 + (t - 64)] = cntl[t - 64];
  } else if (t < 384) {
    const int idx = t - 128;            // [0,256): sl = idx>>6, e = idx&63
    const int slc = idx >> 6, e = idx & 63;
    float P = 0.0f;
#pragma unroll
    for (int b = 0; b < 8; b++) P += pl[(slc * 8 + b) * 68 + e];
    float c1 = P * 0.125f;
    float c2 = c1 * c1;
    c1 = wave_sum64(c1);
    c2 = wave_sum64(c2);
    if (lane == 0) { red8[(w - 2) * 2] = c1; red8[(w - 2) * 2 + 1] = c2; }
  }
  __syncthreads();
  if (t == 0) {
    prt[640] = (red8[0] + red8[2]) + (red8[4] + red8[6]);
    prt[641] = (red8[1] + red8[3]) + (red8[5] + red8[7]);
  }
}

// ---------------- reduce+final fused: last block computes the losses --------
__global__ void router_reduce(float* __restrict__ ws, float* __restrict__ out) {
  const int t = threadIdx.x;
  __shared__ int lastFlag;
  if (t < N_TOT) {
    const int base = blockIdx.x * 32;
    const float* p = ws + WS_PART + (size_t)base * PART_STRIDE + t;
    float acc = 0.0f;
#pragma unroll 8
    for (int i = 0; i < 32; ++i) acc += p[(size_t)i * PART_STRIDE];
    atomicAdd(&ws[WS_TOT + t], acc);
  }
  __syncthreads();                      // drains vmcnt: our atomics complete
  if (t == 0) {
    __threadfence();
    int old = atomicAdd((int*)&ws[WS_FLAG], 1);
    lastFlag = (old == RBLK - 1);
  }
  __syncthreads();
  if (!lastFlag || t >= 64) return;

  // ---- final: 1 wave of the last block ----
  const int lane = t;
  const float* tot = ws + WS_TOT;
  float impsum = 0.0f;
  for (int b = 0; b < B_; ++b) {
    float v = tot[b * 64 + lane];
    float sfull = wave_sum64(v);
    float mean = sfull * (1.0f / 64.0f);
    float d = v - mean;
    float ss = wave_sum64(d * d);
    impsum += (ss / 63.0f) / (mean * mean);
  }
  float importance = impsum * (1.0f / (float)B_);

  const float N = (float)(S_ * E_);
  float meanp = tot[640] / N;
  float varp = tot[641] / N - meanp * meanp;
  float load = varp / (meanp * meanp);

  const float inv_rows = 1.0f / (float)(B_ * S_);
  float te = (tot[576 + lane] * inv_rows) * (tot[512 + lane] * inv_rows);
  float gs = wave_sum64(te) * (float)E_;

  if (lane == 0) {
    out[OUT_GATES + 0] = importance + load;  // aux (GSHARD_W = 0)
    out[OUT_GATES + 1] = gs;
    out[OUT_GATES + 2] = importance;
    out[OUT_GATES + 3] = load;
  }
}

extern "C" void kernel_launch(void* const* d_in, const int* in_sizes, int n_in,
                              void* d_out, int out_size, void* d_ws, size_t ws_size,
                              hipStream_t stream) {
  (void)in_sizes; (void)n_in; (void)out_size; (void)ws_size;
  const float* X     = (const float*)d_in[0];
  const float* noise = (const float*)d_in[1];
  const float* gamma = (const float*)d_in[2];
  const float* beta  = (const float*)d_in[3];
  const float* W     = (const float*)d_in[4];
  float* out = (float*)d_out;
  float* ws  = (float*)d_ws;

  router_prep<<<dim3(E_ + 1), dim3(256), 0, stream>>>(W, gamma, beta, ws);
  router_main<<<dim3(NBLK), dim3(512), 0, stream>>>(X, noise, out, ws);
  router_reduce<<<dim3(RBLK), dim3(704), 0, stream>>>(ws, out);
}

// Round 21
// 56.471 us; speedup vs baseline: 1.0283x; 1.0283x over previous
//
#include <hip/hip_runtime.h>
#include <hip/hip_bf16.h>
#include <math.h>

// NoisyTopExpertsPerItemRouter: B=8,S=4096,D=1024,E=64,K=2
// FINAL (R16 configuration, best measured: 56.4us total):
//   R9 geometry (1024 blk x 8 waves, 32 waves/CU) + XOR-swizzled A-tile
//   (conflict-free ds_read_b128) + lgkm-only K-loop barriers + plain
//   per-block records + 32-block reduce + 1-wave final.
#define B_ 8
#define S_ 4096
#define D_ 1024
#define E_ 64
#define NOISE_STD 0.015625f     // max(1/64, 1e-6)
#define INV_NOISE_STD 64.0f
#define OUT_GATES (B_ * S_ * E_)   // 2097152
#define NBLK 1024                  // main grid = S_/4 (32 rows per block)

typedef __attribute__((ext_vector_type(8))) short short8;
typedef __attribute__((ext_vector_type(4))) float f32x4;

// workspace layout (float offsets)
// [0 .. 32768): Wg as bf16 [64][1024] (ushort)
#define WS_GW   32768                    // GW[64]
#define WS_BW   32832                    // BW[64]
#define WS_PART 32896                    // part[1024][644] per-block records
#define PART_STRIDE 644                  // 512 imp + 64 sgn + 64 cnt + c1 + c2
#define WS_TOT  (WS_PART + NBLK * PART_STRIDE)
#define N_TOT   642

// K-loop barrier WITHOUT the vmcnt(0) drain __syncthreads would emit.
#define LDS_BARRIER() \
  asm volatile("s_waitcnt lgkmcnt(0)\n\ts_barrier" ::: "memory")

__device__ __forceinline__ float wave_sum64(float v) {
#pragma unroll
  for (int o = 32; o > 0; o >>= 1) v += __shfl_xor(v, o);
  return v;
}

// ---------------- prep: Wg(bf16) = gamma*W, GW/BW reductions, zero totals ---
__global__ void router_prep(const float* __restrict__ W,
                            const float* __restrict__ gamma,
                            const float* __restrict__ beta,
                            float* __restrict__ ws) {
  if (blockIdx.x >= E_) {
    for (int i = threadIdx.x; i < N_TOT; i += 256) ws[WS_TOT + i] = 0.0f;
    return;
  }
  const int e = blockIdx.x;
  unsigned short* wgb = (unsigned short*)ws;
  float gw = 0.0f, bw = 0.0f;
  for (int d = threadIdx.x; d < D_; d += 256) {
    float wv = W[e * D_ + d];
    float pv = gamma[d] * wv;
    union { __hip_bfloat16 h; unsigned short u; } cv;
    cv.h = __float2bfloat16(pv);
    wgb[e * D_ + d] = cv.u;
    gw += __bfloat162float(cv.h);   // sum of ROUNDED values (consistency)
    bw += beta[d] * wv;
  }
  __shared__ float sred[8];
  gw = wave_sum64(gw);
  bw = wave_sum64(bw);
  const int w = threadIdx.x >> 6, lane = threadIdx.x & 63;
  if (lane == 0) { sred[w] = gw; sred[4 + w] = bw; }
  __syncthreads();
  if (threadIdx.x == 0) {
    ws[WS_GW + e] = sred[0] + sred[1] + sred[2] + sred[3];
    ws[WS_BW + e] = sred[4] + sred[5] + sred[6] + sred[7];
  }
}

// ---------------- main: R16 verbatim ----------------------------------------
// block = 512 thr = 8 waves; owns 32 rows (r: b=r&7, sl=r>>3, s=4*bid+sl).
// Wave w: rg=w>>2 (16 rows), et=w&3 (16 experts), FULL K -> acc = 1 f32x4.
// A-tile LDS [32][64] float4-XOR swizzle (conflict-free both sides).
// lgkm-only K-loop barriers; X queue depth 2; B ring depth 2.
__global__ void __launch_bounds__(512, 4)
router_main(const float* __restrict__ X, const float* __restrict__ noise,
            float* __restrict__ out, float* __restrict__ ws) {
  __shared__ __align__(16) float unbuf[4352];  // 2 x [32][64] swz staging; -> gcl/gnl
  __shared__ __align__(16) float Lg[2176];     // [32][68] logits; -> pl
  __shared__ float svs[32], sv2s[32];
  __shared__ float cntl[64];
  __shared__ float red8[8];
  float* gcl = unbuf;          // [32][68] clean gates (staging reads done)
  float* gnl = unbuf + 2176;   // [32][68] noisy gates
  float* pl  = Lg;             // per-lane read-then-write -> safe alias

  const int t = threadIdx.x;
  const int w = t >> 6, lane = t & 63;
  const int lrow = lane & 15, kh = lane >> 4;
  const int bid = blockIdx.x;
  const int s0 = bid * 4;

  // staging: thread t -> row r_t = t>>4 (32 rows), float4 c4w = t&15, swizzled
  const int r_t = t >> 4, c4w = t & 15;
  const int ldso = r_t * 64 + ((c4w ^ (r_t & 15)) << 2);
  const float* __restrict__ xstage =
      X + ((size_t)(r_t & 7) * S_ + (size_t)(s0 + (r_t >> 3))) * D_ + c4w * 4;

  // GEMM: wave w -> rg = w>>2 (rows 16rg..16rg+15), et = w&3 (experts 16et..)
  const int rg = w >> 2, et = w & 3;
  const unsigned short* __restrict__ bp =
      (const unsigned short*)ws + (16 * et + lrow) * D_ + kh * 8;
  const float gwv = ws[WS_GW + 16 * et + lrow];
  const float bwv = ws[WS_BW + 16 * et + lrow];

  // A-read swizzled offsets (row&15 == lrow for row = 16rg+lrow)
  const int arow = 16 * rg + lrow;
  const int abase = arow * 64;
  const int a0_0 = abase + (((0 + 2 * kh + 0) ^ lrow) << 2);   // ks=0, c4, +0
  const int a0_1 = abase + (((0 + 2 * kh + 1) ^ lrow) << 2);   // ks=0, c4+1
  const int a1_0 = abase + (((8 + 2 * kh + 0) ^ lrow) << 2);   // ks=1
  const int a1_1 = abase + (((8 + 2 * kh + 1) ^ lrow) << 2);

  // epilogue indices + EARLY noise load (lands during GEMM)
  const int rr_e = lane >> 4, j_e = lane & 15;
  const int r_e = w * 4 + rr_e;                 // [0,32)
  const int b_e = r_e & 7, sl_e = r_e >> 3;
  const int s_e = s0 + sl_e;
  const float4 nv =
      *(const float4*)(noise + ((size_t)b_e * S_ + s_e) * E_ + 4 * j_e);

  // prologue: X regs for steps 0,1; B ring for steps 0,1; stage step 0
  float4 qx[2];
  short8 qb[2][2];
  qx[0] = *(const float4*)(xstage);
  qx[1] = *(const float4*)(xstage + 64);
  qb[0][0] = *(const short8*)(bp);
  qb[0][1] = *(const short8*)(bp + 32);
  qb[1][0] = *(const short8*)(bp + 64);
  qb[1][1] = *(const short8*)(bp + 96);

  float ssv = 0.0f, ssv2 = 0.0f;
  *(float4*)(&unbuf[ldso]) = qx[0];
  ssv  += (qx[0].x + qx[0].y) + (qx[0].z + qx[0].w);
  ssv2 = fmaf(qx[0].x, qx[0].x, ssv2); ssv2 = fmaf(qx[0].y, qx[0].y, ssv2);
  ssv2 = fmaf(qx[0].z, qx[0].z, ssv2); ssv2 = fmaf(qx[0].w, qx[0].w, ssv2);

  f32x4 acc = {0.f, 0.f, 0.f, 0.f};

#pragma unroll
  for (int s = 0; s < 16; ++s) {
    LDS_BARRIER();                         // buf[s&1] staged (no vmcnt drain)
    if (s + 2 < 16)                        // X for step s+2 (slot s&1 now free)
      qx[s & 1] = *(const float4*)(xstage + (s + 2) * 64);

    const float* xb = unbuf + (s & 1) * 2048;
    {
      float4 a0 = *(const float4*)(xb + a0_0);
      float4 a1 = *(const float4*)(xb + a0_1);
      union { short8 s8; __hip_bfloat162 h[4]; } u;
      u.h[0] = __float22bfloat162_rn(make_float2(a0.x, a0.y));
      u.h[1] = __float22bfloat162_rn(make_float2(a0.z, a0.w));
      u.h[2] = __float22bfloat162_rn(make_float2(a1.x, a1.y));
      u.h[3] = __float22bfloat162_rn(make_float2(a1.z, a1.w));
      acc = __builtin_amdgcn_mfma_f32_16x16x32_bf16(u.s8, qb[s & 1][0],
                                                    acc, 0, 0, 0);
    }
    {
      float4 a0 = *(const float4*)(xb + a1_0);
      float4 a1 = *(const float4*)(xb + a1_1);
      union { short8 s8; __hip_bfloat162 h[4]; } u;
      u.h[0] = __float22bfloat162_rn(make_float2(a0.x, a0.y));
      u.h[1] = __float22bfloat162_rn(make_float2(a0.z, a0.w));
      u.h[2] = __float22bfloat162_rn(make_float2(a1.x, a1.y));
      u.h[3] = __float22bfloat162_rn(make_float2(a1.z, a1.w));
      acc = __builtin_amdgcn_mfma_f32_16x16x32_bf16(u.s8, qb[s & 1][1],
                                                    acc, 0, 0, 0);
    }
    if (s + 2 < 16) {                      // refill B ring slot just consumed
      qb[s & 1][0] = *(const short8*)(bp + (s + 2) * 64);
      qb[s & 1][1] = *(const short8*)(bp + (s + 2) * 64 + 32);
    }
    if (s + 1 < 16) {                      // stage step s+1 (issued at s-1)
      float4 wv = qx[(s + 1) & 1];
      *(float4*)(&unbuf[((s + 1) & 1) * 2048 + ldso]) = wv;
      ssv  += (wv.x + wv.y) + (wv.z + wv.w);
      ssv2 = fmaf(wv.x, wv.x, ssv2); ssv2 = fmaf(wv.y, wv.y, ssv2);
      ssv2 = fmaf(wv.z, wv.z, ssv2); ssv2 = fmaf(wv.w, wv.w, ssv2);
    }
  }

  // LN stats: 16 staging threads per row -> shfl reduce within 16-lane group
  ssv  += __shfl_xor(ssv, 1);  ssv  += __shfl_xor(ssv, 2);
  ssv  += __shfl_xor(ssv, 4);  ssv  += __shfl_xor(ssv, 8);
  ssv2 += __shfl_xor(ssv2, 1); ssv2 += __shfl_xor(ssv2, 2);
  ssv2 += __shfl_xor(ssv2, 4); ssv2 += __shfl_xor(ssv2, 8);
  if ((t & 15) == 0) { svs[r_t] = ssv; sv2s[r_t] = ssv2; }
  if (t < 64) cntl[t] = 0.0f;
  __syncthreads();

  // logits: C/D layout col=lane&15, row=(lane>>4)*4+i  [m89-verified]
#pragma unroll
  for (int i = 0; i < 4; i++) {
    const int rloc = 16 * rg + kh * 4 + i;
    const float mui = svs[rloc] * (1.0f / (float)D_);
    const float var = sv2s[rloc] * (1.0f / (float)D_) - mui * mui;
    const float rsi = rsqrtf(var + 1e-5f);
    Lg[rloc * 68 + 16 * et + lrow] = rsi * (acc[i] - mui * gwv) + bwv;
  }
  __syncthreads();   // logits ready; staging reads done -> gcl/gnl reusable

  // ---- epilogue: 8 waves; wave w rows 4w..4w+3; lane=(rr,j), 4 experts ----
  {
    const int r = r_e, b = b_e, s = s_e, j = j_e;
    float4 lv = *(const float4*)(Lg + r * 68 + 4 * j);
    float ln0 = fmaf(NOISE_STD, nv.x, lv.x);
    float ln1 = fmaf(NOISE_STD, nv.y, lv.y);
    float ln2 = fmaf(NOISE_STD, nv.z, lv.z);
    float ln3 = fmaf(NOISE_STD, nv.w, lv.w);

    // combined max+secondmax of noisy logits (m1 also shifts clean softmax)
    float m1 = ln0, m2 = -INFINITY;
    m2 = fmaxf(m2, fminf(m1, ln1)); m1 = fmaxf(m1, ln1);
    m2 = fmaxf(m2, fminf(m1, ln2)); m1 = fmaxf(m1, ln2);
    m2 = fmaxf(m2, fminf(m1, ln3)); m1 = fmaxf(m1, ln3);
#pragma unroll
    for (int o = 1; o <= 8; o <<= 1) {
      float o1 = __shfl_xor(m1, o), o2 = __shfl_xor(m2, o);
      m2 = fmaxf(fmaxf(m2, o2), fminf(m1, o1));
      m1 = fmaxf(m1, o1);
    }
    float ec0 = __expf(lv.x - m1), ec1 = __expf(lv.y - m1);
    float ec2 = __expf(lv.z - m1), ec3 = __expf(lv.w - m1);
    float en0 = __expf(ln0 - m1), en1 = __expf(ln1 - m1);
    float en2 = __expf(ln2 - m1), en3 = __expf(ln3 - m1);
    float sg = (ec0 + ec1) + (ec2 + ec3);
    float sn = (en0 + en1) + (en2 + en3);
#pragma unroll
    for (int o = 1; o <= 8; o <<= 1) {
      sg += __shfl_xor(sg, o);
      sn += __shfl_xor(sn, o);
    }
    const float rg_ = 1.0f / sg, rn_ = 1.0f / sn;
    float4 gnv = { en0 * rn_, en1 * rn_, en2 * rn_, en3 * rn_ };
    float4 gcv = { ec0 * rg_, ec1 * rg_, ec2 * rg_, ec3 * rg_ };
    float z0 = fminf(fmaxf((m2 - lv.x) * INV_NOISE_STD, -10.f), 10.f);
    float z1 = fminf(fmaxf((m2 - lv.y) * INV_NOISE_STD, -10.f), 10.f);
    float z2 = fminf(fmaxf((m2 - lv.z) * INV_NOISE_STD, -10.f), 10.f);
    float z3 = fminf(fmaxf((m2 - lv.w) * INV_NOISE_STD, -10.f), 10.f);
    float4 pv = { 0.5f * (1.0f + erff(z0 * 0.70710678118654752f)),
                  0.5f * (1.0f + erff(z1 * 0.70710678118654752f)),
                  0.5f * (1.0f + erff(z2 * 0.70710678118654752f)),
                  0.5f * (1.0f + erff(z3 * 0.70710678118654752f)) };

    *(float4*)(out + ((size_t)b * S_ + s) * E_ + 4 * j) = gnv;
    *(float4*)(gnl + r * 68 + 4 * j) = gnv;
    *(float4*)(gcl + r * 68 + 4 * j) = gcv;
    *(float4*)(pl  + r * 68 + 4 * j) = pv;
    // top-1 count via equality (ties vanishingly rare; softmax is monotone)
    if (ln0 == m1) atomicAdd(&cntl[4 * j + 0], 1.0f);
    if (ln1 == m1) atomicAdd(&cntl[4 * j + 1], 1.0f);
    if (ln2 == m1) atomicAdd(&cntl[4 * j + 2], 1.0f);
    if (ln3 == m1) atomicAdd(&cntl[4 * j + 3], 1.0f);
  }
  __syncthreads();

  // ---- phase 2: block reductions -> PLAIN per-block record (no atomics) ----
  float* prt = ws + WS_PART + (size_t)bid * PART_STRIDE;
  {
    // importance: thread t -> (b = t>>6, e = t&63), sum over 4 sl
    const int b0i = t >> 6, e0i = t & 63;
    float v = gcl[(0 * 8 + b0i) * 68 + e0i] + gcl[(1 * 8 + b0i) * 68 + e0i] +
              gcl[(2 * 8 + b0i) * 68 + e0i] + gcl[(3 * 8 + b0i) * 68 + e0i];
    prt[t] = v;
  }
  if (t < 64) {
    float sgn = 0.0f;
#pragma unroll
    for (int r = 0; r < 32; r++) sgn += gnl[r * 68 + t];
    prt[512 + t] = sgn;
  } else if (t < 128) {
    prt[576 + (t - 64)] = cntl[t - 64];
  } else if (t < 384) {
    const int idx = t - 128;            // [0,256): sl = idx>>6, e = idx&63
    const int slc = idx >> 6, e = idx & 63;
    float P = 0.0f;
#pragma unroll
    for (int b = 0; b < 8; b++) P += pl[(slc * 8 + b) * 68 + e];
    float c1 = P * 0.125f;
    float c2 = c1 * c1;
    c1 = wave_sum64(c1);
    c2 = wave_sum64(c2);
    if (lane == 0) { red8[(w - 2) * 2] = c1; red8[(w - 2) * 2 + 1] = c2; }
  }
  __syncthreads();
  if (t == 0) {
    prt[640] = (red8[0] + red8[2]) + (red8[4] + red8[6]);
    prt[641] = (red8[1] + red8[3]) + (red8[5] + red8[7]);
  }
}

// ---------------- reduce: 32 blocks x 32 records, deep unroll ---------------
__global__ void router_reduce(float* __restrict__ ws) {
  const int t = threadIdx.x;
  if (t >= N_TOT) return;
  const int base = blockIdx.x * 32;
  const float* p = ws + WS_PART + (size_t)base * PART_STRIDE + t;
  float acc = 0.0f;
#pragma unroll 8
  for (int i = 0; i < 32; ++i) acc += p[(size_t)i * PART_STRIDE];
  atomicAdd(&ws[WS_TOT + t], acc);
}

// ---------------- finalize: 3 scalar losses from totals ---------------------
__global__ void router_final(const float* __restrict__ ws, float* __restrict__ out) {
  const int lane = threadIdx.x;  // 64 threads = 1 wave
  const float* tot = ws + WS_TOT;
  float impsum = 0.0f;
  for (int b = 0; b < B_; ++b) {
    float v = tot[b * 64 + lane];
    float sfull = wave_sum64(v);
    float mean = sfull * (1.0f / 64.0f);
    float d = v - mean;
    float ss = wave_sum64(d * d);
    impsum += (ss / 63.0f) / (mean * mean);
  }
  float importance = impsum * (1.0f / (float)B_);

  const float N = (float)(S_ * E_);
  float meanp = tot[640] / N;
  float varp = tot[641] / N - meanp * meanp;
  float load = varp / (meanp * meanp);

  const float inv_rows = 1.0f / (float)(B_ * S_);
  float te = (tot[576 + lane] * inv_rows) * (tot[512 + lane] * inv_rows);
  float gs = wave_sum64(te) * (float)E_;

  if (lane == 0) {
    out[OUT_GATES + 0] = importance + load;  // aux (GSHARD_W = 0)
    out[OUT_GATES + 1] = gs;
    out[OUT_GATES + 2] = importance;
    out[OUT_GATES + 3] = load;
  }
}

extern "C" void kernel_launch(void* const* d_in, const int* in_sizes, int n_in,
                              void* d_out, int out_size, void* d_ws, size_t ws_size,
                              hipStream_t stream) {
  (void)in_sizes; (void)n_in; (void)out_size; (void)ws_size;
  const float* X     = (const float*)d_in[0];
  const float* noise = (const float*)d_in[1];
  const float* gamma = (const float*)d_in[2];
  const float* beta  = (const float*)d_in[3];
  const float* W     = (const float*)d_in[4];
  float* out = (float*)d_out;
  float* ws  = (float*)d_ws;

  router_prep<<<dim3(E_ + 1), dim3(256), 0, stream>>>(W, gamma, beta, ws);
  router_main<<<dim3(NBLK), dim3(512), 0, stream>>>(X, noise, out, ws);
  router_reduce<<<dim3(32), dim3(704), 0, stream>>>(ws);
  router_final<<<dim3(1), dim3(64), 0, stream>>>(ws, out);
}